// Round 4
// baseline (2170.746 us; speedup 1.0000x reference)
//
#include <hip/hip_runtime.h>
#include <math.h>

#define PI_D 3.14159265358979323846

#define REP32(M) M(0) M(1) M(2) M(3) M(4) M(5) M(6) M(7) M(8) M(9) M(10) M(11) \
    M(12) M(13) M(14) M(15) M(16) M(17) M(18) M(19) M(20) M(21) M(22) M(23) \
    M(24) M(25) M(26) M(27) M(28) M(29) M(30) M(31)

// ---------------- tables ----------------
// tz2[z][k][2]: {2*cos(2pi z k/40)/163840, -2*sin(2pi z k/40)/163840}, k=0 row = {1/163840, 0}
__global__ void k_tables(float* tzf, float* tzi, float* tz2, float* txf, float* txi) {
    int t = blockIdx.x * blockDim.x + threadIdx.x;
    if (t < 320) {
        int z = t >> 3, k = t & 7;
        double ang = -2.0 * PI_D * (double)(z * k) / 40.0;
        tzf[t * 2] = (float)cos(ang); tzf[t * 2 + 1] = (float)sin(ang);
        tzi[t * 2] = (float)cos(-ang); tzi[t * 2 + 1] = (float)sin(-ang);
        double s = 1.0 / 163840.0;
        double f = (k == 0) ? s : 2.0 * s;
        tz2[t * 2] = (float)(f * cos(-ang));
        tz2[t * 2 + 1] = (k == 0) ? 0.0f : (float)(-f * sin(-ang));
    }
    if (t < 1472) {
        int xx = t / 23, m = t % 23;
        double ang = -2.0 * PI_D * (double)(xx * (m - 11)) / 64.0;
        txf[t * 2] = (float)cos(ang); txf[t * 2 + 1] = (float)sin(ang);
        txi[t * 2] = (float)cos(-ang); txi[t * 2 + 1] = (float)sin(-ang);
    }
}

// transpose mlp_w2 and w_w for all 4 layers: w2t[l][j][o] = w2[l][o][j]
__global__ void k_wtrans(const float* __restrict__ w2, const float* __restrict__ ww,
                         float* __restrict__ w2t, float* __restrict__ wwt) {
    int gid = blockIdx.x * blockDim.x + threadIdx.x;
    if (gid < 16384) {
        int l = gid >> 12, r = gid & 4095, o = r >> 6, i = r & 63;
        w2t[l * 4096 + i * 64 + o] = w2[l * 4096 + o * 64 + i];
        wwt[l * 4096 + i * 64 + o] = ww[l * 4096 + o * 64 + i];
    }
}

// ---------------- lift ----------------
__global__ void k_lift(const float* __restrict__ xin, const float* __restrict__ pw,
                       const float* __restrict__ pb, float* __restrict__ xo) {
    int gid = blockIdx.x * 256 + threadIdx.x;   // 327680 total
    int b = gid / 163840, p = gid % 163840;
    int y = p / 2560, xx = (p / 40) % 64, z = p % 40;
    float v[13];
#pragma unroll
    for (int i = 0; i < 10; i++) v[i] = xin[(size_t)gid * 10 + i];
    v[10] = (float)((double)y / 63.0);
    v[11] = (float)((double)xx / 63.0);
    v[12] = (float)((double)z / 39.0);
    size_t ob = (size_t)b * 10485760 + p;
    for (int c = 0; c < 64; c++) {
        float a = pb[c];
#pragma unroll
        for (int i = 0; i < 13; i++) a += pw[c * 13 + i] * v[i];
        xo[ob + (size_t)c * 163840] = a;
    }
}

// ---------------- forward z-DFT (r2c, 8 modes) fused with x-DFT (64 -> 23 modes) ----
__global__ void k_fwd_zx(const float* __restrict__ x, const float* __restrict__ tzf,
                         const float* __restrict__ txf, float* __restrict__ Fx) {
    int bid = blockIdx.x;
    int b = bid >> 12, c = (bid >> 6) & 63, y = bid & 63;
    int t = threadIdx.x;
    __shared__ float xr_[2560];
    __shared__ float f1[1024];
    __shared__ float tzs[640];
    const float* xrow = x + ((size_t)((b * 64 + c) * 4096 + y * 64)) * 40;
    for (int idx = t; idx < 2560; idx += 256) xr_[idx] = xrow[idx];
    for (int idx = t; idx < 640; idx += 256) tzs[idx] = tzf[idx];
    __syncthreads();
    for (int q = t; q < 512; q += 256) {
        int xx = q >> 3, k = q & 7;
        float sr = 0.f, si = 0.f;
        for (int z = 0; z < 40; z++) {
            float v = xr_[xx * 40 + z];
            sr += v * tzs[(z * 8 + k) * 2];
            si += v * tzs[(z * 8 + k) * 2 + 1];
        }
        f1[(xx * 8 + k) * 2] = sr;
        f1[(xx * 8 + k) * 2 + 1] = si;
    }
    __syncthreads();
    if (t < 184) {
        int m = t >> 3, k = t & 7;
        float sr = 0.f, si = 0.f;
        for (int xx = 0; xx < 64; xx++) {
            float ar = f1[(xx * 8 + k) * 2], ai = f1[(xx * 8 + k) * 2 + 1];
            float tr = txf[(xx * 23 + m) * 2], ti = txf[(xx * 23 + m) * 2 + 1];
            sr += ar * tr - ai * ti;
            si += ar * ti + ai * tr;
        }
        size_t g = ((size_t)(((b * 64 + c) * 64 + y) * 23 + m) * 8 + k) * 2;
        Fx[g] = sr; Fx[g + 1] = si;
    }
}

// ---------------- forward y-DFT (64 -> 23 modes) ----------------
__global__ void k_fwd_y(const float* __restrict__ Fx, const float* __restrict__ txf,
                        float* __restrict__ Xs) {
    int bid = blockIdx.x;
    int b = bid / 1472, rem = bid % 1472, c = rem / 23, m = rem % 23;
    int t = threadIdx.x;
    __shared__ float s[1024];  // [y][k][2]
    for (int idx = t; idx < 512; idx += 192) {
        int y = idx >> 3, k = idx & 7;
        size_t g = ((size_t)(((b * 64 + c) * 64 + y) * 23 + m) * 8 + k) * 2;
        s[idx * 2] = Fx[g]; s[idx * 2 + 1] = Fx[g + 1];
    }
    __syncthreads();
    if (t < 184) {
        int n = t >> 3, k = t & 7;
        float sr = 0.f, si = 0.f;
        for (int y = 0; y < 64; y++) {
            float ar = s[(y * 8 + k) * 2], ai = s[(y * 8 + k) * 2 + 1];
            float tr = txf[(y * 23 + n) * 2], ti = txf[(y * 23 + n) * 2 + 1];
            sr += ar * tr - ai * ti;
            si += ar * ti + ai * tr;
        }
        size_t g = ((size_t)(((b * 64 + c) * 23 + n) * 23 + m) * 8 + k) * 2;
        Xs[g] = sr; Xs[g + 1] = si;
    }
}

// ---------------- mode mixing with on-the-fly radial-weight gather ----------------
__global__ void k_mix(const float* __restrict__ Xs, const float* __restrict__ WLC,
                      const float* __restrict__ WLR, float* __restrict__ Md) {
    int bid = blockIdx.x;
    int n = bid / 23, m = bid % 23;
    int a = n, c = m, yy, w;
    if (c >= 11) { yy = a; w = c - 11; } else { yy = 22 - a; w = 11 - c; }
    int isLC, idx;
    if (yy >= 12) {
        int p = yy - 12, q = w;
        if (q == 0) { isLC = 1; idx = p + 1; } else { isLC = 0; idx = p * 11 + (q - 1); }
    } else {
        if (w == 0) { isLC = 1; idx = 11 - yy; }
        else {
            int p = w - 1, q = 11 - yy;
            if (q == 0) { isLC = 1; idx = p + 1; } else { isLC = 0; idx = p * 11 + (q - 1); }
        }
    }
    const float* src = isLC ? WLC : WLR;
    int stride = isLC ? 96 : 968;
    int base8 = idx * 8;

    int t = threadIdx.x;
    int o = t >> 3, tt = t & 7;
    __shared__ __align__(16) float wl[8 * 64 * 8];
    __shared__ float xl[256];
    float aR0 = 0.f, aI0 = 0.f, aR1 = 0.f, aI1 = 0.f;
    for (int i0 = 0; i0 < 64; i0 += 8) {
        {
            int il = t >> 6, oo = t & 63;
            const float4* g = (const float4*)(src + (size_t)((i0 + il) * 64 + oo) * stride + base8);
            float4 A = g[0], B = g[1];
            float4* d = (float4*)&wl[(il * 64 + oo) * 8];
            d[0] = A; d[1] = B;
        }
        if (t < 256) {
            int bb = t >> 7, il = (t >> 4) & 7, kk = (t >> 1) & 7, ri = t & 1;
            xl[t] = Xs[((size_t)(((bb * 64 + i0 + il) * 23 + n) * 23 + m) * 8 + kk) * 2 + ri];
        }
        __syncthreads();
#pragma unroll
        for (int il = 0; il < 8; il++) {
            float wv = wl[(il * 64 + o) * 8 + tt];
            float xr0 = xl[(il * 8 + tt) * 2], xi0 = xl[(il * 8 + tt) * 2 + 1];
            float xr1 = xl[128 + (il * 8 + tt) * 2], xi1 = xl[128 + (il * 8 + tt) * 2 + 1];
            aR0 += wv * xr0; aI0 += wv * xi0;
            aR1 += wv * xr1; aI1 += wv * xi1;
        }
        __syncthreads();
    }
    size_t ob0 = ((size_t)((o * 23 + n) * 23 + m) * 8 + tt) * 2;
    size_t ob1 = ((size_t)(((64 + o) * 23 + n) * 23 + m) * 8 + tt) * 2;
    Md[ob0] = aR0; Md[ob0 + 1] = aI0;
    Md[ob1] = aR1; Md[ob1 + 1] = aI1;
}

// ---------------- inverse y (23 -> 64) ----------------
__global__ void k_inv_y(const float* __restrict__ Md, const float* __restrict__ txi,
                        float* __restrict__ T1) {
    int bid = blockIdx.x;
    int b = bid / 1472, rem = bid % 1472, o = rem / 23, m = rem % 23;
    int t = threadIdx.x;
    __shared__ float s[368];  // [n][k][2]
    if (t < 184) {
        int n = t >> 3, kk = t & 7;
        size_t g = ((size_t)(((b * 64 + o) * 23 + n) * 23 + m) * 8 + kk) * 2;
        s[t * 2] = Md[g]; s[t * 2 + 1] = Md[g + 1];
    }
    __syncthreads();
    int y = t >> 3, k = t & 7;
    float sr = 0.f, si = 0.f;
    for (int n = 0; n < 23; n++) {
        float ar = s[(n * 8 + k) * 2], ai = s[(n * 8 + k) * 2 + 1];
        float tr = txi[(y * 23 + n) * 2], ti = txi[(y * 23 + n) * 2 + 1];
        sr += ar * tr - ai * ti;
        si += ar * ti + ai * tr;
    }
    size_t g = ((size_t)(((b * 64 + o) * 64 + y) * 23 + m) * 8 + k) * 2;
    T1[g] = sr; T1[g + 1] = si;
}

// ---------------- inverse x (23 -> 64) ----------------
__global__ void k_inv_x(const float* __restrict__ T1, const float* __restrict__ txi,
                        float* __restrict__ T2) {
    int bid = blockIdx.x;
    int b = bid >> 12, o = (bid >> 6) & 63, y = bid & 63;
    int t = threadIdx.x;
    __shared__ float s[368];  // [m][k][2]
    if (t < 184) {
        size_t g = (size_t)(((b * 64 + o) * 64 + y)) * 368 + t * 2;
        s[t * 2] = T1[g]; s[t * 2 + 1] = T1[g + 1];
    }
    __syncthreads();
    int xx = t >> 3, k = t & 7;
    float sr = 0.f, si = 0.f;
    for (int m = 0; m < 23; m++) {
        float ar = s[(m * 8 + k) * 2], ai = s[(m * 8 + k) * 2 + 1];
        float tr = txi[(xx * 23 + m) * 2], ti = txi[(xx * 23 + m) * 2 + 1];
        sr += ar * tr - ai * ti;
        si += ar * ti + ai * tr;
    }
    size_t g = ((size_t)((b * 64 + o) * 4096 + y * 64 + xx) * 8 + k) * 2;
    T2[g] = sr; T2[g + 1] = si;
}

// ---------------- inline erf-based GELU (A&S 7.1.26, |err|<=1.5e-7) ----
__device__ __forceinline__ float gelu_fast(float x) {
    float u = x * 0.70710678118654752f;
    float a = fabsf(u);
    float t = 1.0f / (1.0f + 0.3275911f * a);
    float poly = t * (0.254829592f + t * (-0.284496736f + t * (1.421413741f +
                 t * (-1.453152027f + t * 1.061405429f))));
    float erfa = 1.0f - poly * __expf(-a * a);
    float er = copysignf(erfa, u);
    return 0.5f * x * (1.0f + er);
}

// ---------------- mlp1: c2r inverse-z + GEMM1 + gelu -> g[j][P] ----------------
// 32 named accumulators per j-chunk (2 chunks); x1 recomputed per chunk from
// T2 rows (global dwordx4, block slice ~28KB -> L1-hot 2nd chunk). No arrays.
__global__ __launch_bounds__(256, 4) void k_mlp1(
    const float* __restrict__ t2buf, const float* __restrict__ w1,
    const float* __restrict__ b1, const float* __restrict__ tz2,
    float* __restrict__ g) {
    int gid = blockIdx.x * 256 + threadIdx.x;  // 327680
    int b = gid / 163840, p = gid % 163840;
    int y = p / 2560, xx = (p / 40) % 64, z = p % 40;
    const float4* tzp = (const float4*)(tz2 + z * 16);
    float4 Tz0 = tzp[0], Tz1 = tzp[1], Tz2 = tzp[2], Tz3 = tzp[3];
    float tc0 = Tz0.x, ts0 = Tz0.y, tc1 = Tz0.z, ts1 = Tz0.w;
    float tc2 = Tz1.x, ts2 = Tz1.y, tc3 = Tz1.z, ts3 = Tz1.w;
    float tc4 = Tz2.x, ts4 = Tz2.y, tc5 = Tz2.z, ts5 = Tz2.w;
    float tc6 = Tz3.x, ts6 = Tz3.y, tc7 = Tz3.z, ts7 = Tz3.w;
    size_t rowbase = ((size_t)(b * 64) * 4096 + y * 64 + xx) * 16;
    for (int jc = 0; jc < 64; jc += 32) {
#define DECL(n) float h##n = b1[jc + n];
        REP32(DECL)
#undef DECL
        for (int i = 0; i < 64; i++) {
            const float4* rp = (const float4*)(t2buf + rowbase + (size_t)i * 65536);
            float4 A = rp[0], B = rp[1], C = rp[2], D = rp[3];
            float xi = A.x * tc0;              // k=0: Im(DC) dropped (ts0=0)
            xi = fmaf(A.z, tc1, xi); xi = fmaf(A.w, ts1, xi);
            xi = fmaf(B.x, tc2, xi); xi = fmaf(B.y, ts2, xi);
            xi = fmaf(B.z, tc3, xi); xi = fmaf(B.w, ts3, xi);
            xi = fmaf(C.x, tc4, xi); xi = fmaf(C.y, ts4, xi);
            xi = fmaf(C.z, tc5, xi); xi = fmaf(C.w, ts5, xi);
            xi = fmaf(D.x, tc6, xi); xi = fmaf(D.y, ts6, xi);
            xi = fmaf(D.z, tc7, xi); xi = fmaf(D.w, ts7, xi);
#define FMA(n) h##n = fmaf(w1[(jc + n) * 64 + i], xi, h##n);
            REP32(FMA)
#undef FMA
        }
#define STO(n) g[(size_t)(jc + n) * 327680 + gid] = gelu_fast(h##n);
        REP32(STO)
#undef STO
    }
}

// ---------------- mlp2: GEMM2 + skip + relu, in-place on x ----------------
// x columns staged in LDS [ch][pt] (conflict-free, also makes in-place safe);
// g streamed from global (re-read 2x); 32 named accumulators per o-chunk.
__global__ __launch_bounds__(256, 4) void k_mlp2(
    const float* __restrict__ g, float* __restrict__ x,
    const float* __restrict__ w2t, const float* __restrict__ b2,
    const float* __restrict__ wwt, const float* __restrict__ wb, int dorelu) {
    __shared__ float xs[16384];  // [64ch][256pt]
    int t = threadIdx.x;
    int P0 = blockIdx.x * 256;
    int b = P0 / 163840, p0 = P0 % 163840;
    size_t sbase = (size_t)b * 10485760 + p0;
    for (int idx = t; idx < 16384; idx += 256) {
        int i = idx >> 8, pp = idx & 255;
        xs[idx] = x[sbase + (size_t)i * 163840 + pp];
    }
    __syncthreads();
    for (int oc = 0; oc < 64; oc += 32) {
#define DECL(n) float h##n = b2[oc + n] + wb[oc + n];
        REP32(DECL)
#undef DECL
        for (int j = 0; j < 64; j++) {
            float gj = g[(size_t)j * 327680 + P0 + t];
#define FMA(n) h##n = fmaf(w2t[j * 64 + oc + n], gj, h##n);
            REP32(FMA)
#undef FMA
        }
        for (int i = 0; i < 64; i++) {
            float xi = xs[i * 256 + t];
#define FMA(n) h##n = fmaf(wwt[i * 64 + oc + n], xi, h##n);
            REP32(FMA)
#undef FMA
        }
        if (dorelu) {
#define STO(n) x[sbase + (size_t)(oc + n) * 163840 + t] = fmaxf(h##n, 0.0f);
            REP32(STO)
#undef STO
        } else {
#define STO(n) x[sbase + (size_t)(oc + n) * 163840 + t] = h##n;
            REP32(STO)
#undef STO
        }
    }
}

// ---------------- final head ----------------
__global__ __launch_bounds__(256, 4) void k_head(
    const float* __restrict__ xcur,
    const float* __restrict__ qw1, const float* __restrict__ qb1,
    const float* __restrict__ qw2, const float* __restrict__ qb2,
    float* __restrict__ outp) {
    __shared__ float xs[16384];  // [64ch][256pt]
    int t = threadIdx.x;
    int P0 = blockIdx.x * 256;
    int b = P0 / 163840, p0 = P0 % 163840;
    size_t sbase = (size_t)b * 10485760 + p0;
    for (int idx = t; idx < 16384; idx += 256) {
        int i = idx >> 8, pp = idx & 255;
        xs[idx] = xcur[sbase + (size_t)i * 163840 + pp];
    }
    __syncthreads();
    float acc = qb2[0];
    for (int jc = 0; jc < 256; jc += 32) {
#define DECL(n) float h##n = qb1[jc + n];
        REP32(DECL)
#undef DECL
        for (int i = 0; i < 64; i++) {
            float xi = xs[i * 256 + t];
#define FMA(n) h##n = fmaf(qw1[(jc + n) * 64 + i], xi, h##n);
            REP32(FMA)
#undef FMA
        }
#define OUT(n) acc += qw2[jc + n] * gelu_fast(h##n);
        REP32(OUT)
#undef OUT
    }
    outp[P0 + t] = acc;
}

extern "C" void kernel_launch(void* const* d_in, const int* in_sizes, int n_in,
                              void* d_out, int out_size, void* d_ws, size_t ws_size,
                              hipStream_t stream) {
    const float* x_in = (const float*)d_in[0];
    const float* p_w  = (const float*)d_in[1];
    const float* p_b  = (const float*)d_in[2];
    const float* W_LC = (const float*)d_in[3];
    const float* W_LR = (const float*)d_in[4];
    const float* m_w1 = (const float*)d_in[5];
    const float* m_b1 = (const float*)d_in[6];
    const float* m_w2 = (const float*)d_in[7];
    const float* m_b2 = (const float*)d_in[8];
    const float* w_w  = (const float*)d_in[9];
    const float* w_b  = (const float*)d_in[10];
    const float* q_w1 = (const float*)d_in[11];
    const float* q_b1 = (const float*)d_in[12];
    const float* q_w2 = (const float*)d_in[13];
    const float* q_b2 = (const float*)d_in[14];

    char* ws = (char*)d_ws;
    // packed table region [0, 32768)
    float* tzf = (float*)(ws + 0);        // 2560 B
    float* tzi = (float*)(ws + 2560);     // 2560 B
    float* tz2 = (float*)(ws + 5120);     // 2560 B (16B-aligned)
    float* txf = (float*)(ws + 7680);     // 11776 B
    float* txi = (float*)(ws + 19456);    // 11776 B -> ends 31232
    float* w2t = (float*)(ws + 32768);
    float* wwt = (float*)(ws + 32768 + 65536);
    size_t off = 32768 + 131072;
    float* xA = (float*)(ws + off); off += 83886080ull;
    float* gbuf = (float*)(ws + off); off += 83886080ull;   // g[j][P]
    float* Fx = (float*)(ws + off); off += 12058624ull;
    float* Xs = (float*)(ws + off); off += 4333568ull;
    float* Md = (float*)(ws + off); off += 4333568ull;
    float* T1 = (float*)(ws + off); off += 12058624ull;
    float* T2 = (float*)(ws + off); off += 33554432ull;

    k_tables<<<6, 256, 0, stream>>>(tzf, tzi, tz2, txf, txi);
    k_wtrans<<<64, 256, 0, stream>>>(m_w2, w_w, w2t, wwt);
    k_lift<<<1280, 256, 0, stream>>>(x_in, p_w, p_b, xA);

    for (int l = 0; l < 4; l++) {
        k_fwd_zx<<<8192, 256, 0, stream>>>(xA, tzf, txf, Fx);
        k_fwd_y<<<2944, 192, 0, stream>>>(Fx, txf, Xs);
        k_mix<<<529, 512, 0, stream>>>(Xs, W_LC + (size_t)l * 393216,
                                       W_LR + (size_t)l * 3964928, Md);
        k_inv_y<<<2944, 512, 0, stream>>>(Md, txi, T1);
        k_inv_x<<<8192, 512, 0, stream>>>(T1, txi, T2);
        k_mlp1<<<1280, 256, 0, stream>>>(T2, m_w1 + (size_t)l * 4096, m_b1 + l * 64,
                                         tz2, gbuf);
        k_mlp2<<<1280, 256, 0, stream>>>(gbuf, xA, w2t + (size_t)l * 4096, m_b2 + l * 64,
                                         wwt + (size_t)l * 4096, w_b + l * 64,
                                         (l < 3) ? 1 : 0);
    }
    k_head<<<1280, 256, 0, stream>>>(xA, q_w1, q_b1, q_w2, q_b2, (float*)d_out);
}

// Round 5
// 1712.637 us; speedup vs baseline: 1.2675x; 1.2675x over previous
//
#include <hip/hip_runtime.h>
#include <math.h>

#define PI_D 3.14159265358979323846

#define REP64(M) M(0) M(1) M(2) M(3) M(4) M(5) M(6) M(7) M(8) M(9) M(10) M(11) \
    M(12) M(13) M(14) M(15) M(16) M(17) M(18) M(19) M(20) M(21) M(22) M(23) \
    M(24) M(25) M(26) M(27) M(28) M(29) M(30) M(31) M(32) M(33) M(34) M(35) \
    M(36) M(37) M(38) M(39) M(40) M(41) M(42) M(43) M(44) M(45) M(46) M(47) \
    M(48) M(49) M(50) M(51) M(52) M(53) M(54) M(55) M(56) M(57) M(58) M(59) \
    M(60) M(61) M(62) M(63)

// ---------------- tables ----------------
// tz2[z][k][2]: {2*cos(2pi z k/40)/163840, -2*sin(2pi z k/40)/163840}, k=0 row = {1/163840, 0}
__global__ void k_tables(float* tzf, float* tzi, float* tz2, float* txf, float* txi) {
    int t = blockIdx.x * blockDim.x + threadIdx.x;
    if (t < 320) {
        int z = t >> 3, k = t & 7;
        double ang = -2.0 * PI_D * (double)(z * k) / 40.0;
        tzf[t * 2] = (float)cos(ang); tzf[t * 2 + 1] = (float)sin(ang);
        tzi[t * 2] = (float)cos(-ang); tzi[t * 2 + 1] = (float)sin(-ang);
        double s = 1.0 / 163840.0;
        double f = (k == 0) ? s : 2.0 * s;
        tz2[t * 2] = (float)(f * cos(-ang));
        tz2[t * 2 + 1] = (k == 0) ? 0.0f : (float)(-f * sin(-ang));
    }
    if (t < 1472) {
        int xx = t / 23, m = t % 23;
        double ang = -2.0 * PI_D * (double)(xx * (m - 11)) / 64.0;
        txf[t * 2] = (float)cos(ang); txf[t * 2 + 1] = (float)sin(ang);
        txi[t * 2] = (float)cos(-ang); txi[t * 2 + 1] = (float)sin(-ang);
    }
}

// transposes: w2t[l][j][o]=w2[l][o][j]; wwt[l][i][o]=ww[l][o][i]; w1t[l][i][j]=w1[l][j][i]
__global__ void k_wtrans(const float* __restrict__ w2, const float* __restrict__ ww,
                         const float* __restrict__ w1,
                         float* __restrict__ w2t, float* __restrict__ wwt,
                         float* __restrict__ w1t) {
    int gid = blockIdx.x * blockDim.x + threadIdx.x;
    if (gid < 16384) {
        int l = gid >> 12, r = gid & 4095, o = r >> 6, i = r & 63;
        w2t[l * 4096 + i * 64 + o] = w2[l * 4096 + o * 64 + i];
        wwt[l * 4096 + i * 64 + o] = ww[l * 4096 + o * 64 + i];
        w1t[l * 4096 + i * 64 + o] = w1[l * 4096 + o * 64 + i];
    }
}

// ---------------- lift ----------------
__global__ void k_lift(const float* __restrict__ xin, const float* __restrict__ pw,
                       const float* __restrict__ pb, float* __restrict__ xo) {
    int gid = blockIdx.x * 256 + threadIdx.x;   // 327680 total
    int b = gid / 163840, p = gid % 163840;
    int y = p / 2560, xx = (p / 40) % 64, z = p % 40;
    float v[13];
#pragma unroll
    for (int i = 0; i < 10; i++) v[i] = xin[(size_t)gid * 10 + i];
    v[10] = (float)((double)y / 63.0);
    v[11] = (float)((double)xx / 63.0);
    v[12] = (float)((double)z / 39.0);
    size_t ob = (size_t)b * 10485760 + p;
    for (int c = 0; c < 64; c++) {
        float a = pb[c];
#pragma unroll
        for (int i = 0; i < 13; i++) a += pw[c * 13 + i] * v[i];
        xo[ob + (size_t)c * 163840] = a;
    }
}

// ---------------- forward z-DFT (r2c, 8 modes) fused with x-DFT (64 -> 23 modes) ----
__global__ void k_fwd_zx(const float* __restrict__ x, const float* __restrict__ tzf,
                         const float* __restrict__ txf, float* __restrict__ Fx) {
    int bid = blockIdx.x;
    int b = bid >> 12, c = (bid >> 6) & 63, y = bid & 63;
    int t = threadIdx.x;
    __shared__ float xr_[2560];
    __shared__ float f1[1024];
    __shared__ float tzs[640];
    const float* xrow = x + ((size_t)((b * 64 + c) * 4096 + y * 64)) * 40;
    for (int idx = t; idx < 2560; idx += 256) xr_[idx] = xrow[idx];
    for (int idx = t; idx < 640; idx += 256) tzs[idx] = tzf[idx];
    __syncthreads();
    for (int q = t; q < 512; q += 256) {
        int xx = q >> 3, k = q & 7;
        float sr = 0.f, si = 0.f;
        for (int z = 0; z < 40; z++) {
            float v = xr_[xx * 40 + z];
            sr += v * tzs[(z * 8 + k) * 2];
            si += v * tzs[(z * 8 + k) * 2 + 1];
        }
        f1[(xx * 8 + k) * 2] = sr;
        f1[(xx * 8 + k) * 2 + 1] = si;
    }
    __syncthreads();
    if (t < 184) {
        int m = t >> 3, k = t & 7;
        float sr = 0.f, si = 0.f;
        for (int xx = 0; xx < 64; xx++) {
            float ar = f1[(xx * 8 + k) * 2], ai = f1[(xx * 8 + k) * 2 + 1];
            float tr = txf[(xx * 23 + m) * 2], ti = txf[(xx * 23 + m) * 2 + 1];
            sr += ar * tr - ai * ti;
            si += ar * ti + ai * tr;
        }
        size_t g = ((size_t)(((b * 64 + c) * 64 + y) * 23 + m) * 8 + k) * 2;
        Fx[g] = sr; Fx[g + 1] = si;
    }
}

// ---------------- forward y-DFT (64 -> 23 modes) ----------------
__global__ void k_fwd_y(const float* __restrict__ Fx, const float* __restrict__ txf,
                        float* __restrict__ Xs) {
    int bid = blockIdx.x;
    int b = bid / 1472, rem = bid % 1472, c = rem / 23, m = rem % 23;
    int t = threadIdx.x;
    __shared__ float s[1024];  // [y][k][2]
    for (int idx = t; idx < 512; idx += 192) {
        int y = idx >> 3, k = idx & 7;
        size_t g = ((size_t)(((b * 64 + c) * 64 + y) * 23 + m) * 8 + k) * 2;
        s[idx * 2] = Fx[g]; s[idx * 2 + 1] = Fx[g + 1];
    }
    __syncthreads();
    if (t < 184) {
        int n = t >> 3, k = t & 7;
        float sr = 0.f, si = 0.f;
        for (int y = 0; y < 64; y++) {
            float ar = s[(y * 8 + k) * 2], ai = s[(y * 8 + k) * 2 + 1];
            float tr = txf[(y * 23 + n) * 2], ti = txf[(y * 23 + n) * 2 + 1];
            sr += ar * tr - ai * ti;
            si += ar * ti + ai * tr;
        }
        size_t g = ((size_t)(((b * 64 + c) * 23 + n) * 23 + m) * 8 + k) * 2;
        Xs[g] = sr; Xs[g + 1] = si;
    }
}

// ---------------- mode mixing with on-the-fly radial-weight gather ----------------
__global__ void k_mix(const float* __restrict__ Xs, const float* __restrict__ WLC,
                      const float* __restrict__ WLR, float* __restrict__ Md) {
    int bid = blockIdx.x;
    int n = bid / 23, m = bid % 23;
    int a = n, c = m, yy, w;
    if (c >= 11) { yy = a; w = c - 11; } else { yy = 22 - a; w = 11 - c; }
    int isLC, idx;
    if (yy >= 12) {
        int p = yy - 12, q = w;
        if (q == 0) { isLC = 1; idx = p + 1; } else { isLC = 0; idx = p * 11 + (q - 1); }
    } else {
        if (w == 0) { isLC = 1; idx = 11 - yy; }
        else {
            int p = w - 1, q = 11 - yy;
            if (q == 0) { isLC = 1; idx = p + 1; } else { isLC = 0; idx = p * 11 + (q - 1); }
        }
    }
    const float* src = isLC ? WLC : WLR;
    int stride = isLC ? 96 : 968;
    int base8 = idx * 8;

    int t = threadIdx.x;
    int o = t >> 3, tt = t & 7;
    __shared__ __align__(16) float wl[8 * 64 * 8];
    __shared__ float xl[256];
    float aR0 = 0.f, aI0 = 0.f, aR1 = 0.f, aI1 = 0.f;
    for (int i0 = 0; i0 < 64; i0 += 8) {
        {
            int il = t >> 6, oo = t & 63;
            const float4* g = (const float4*)(src + (size_t)((i0 + il) * 64 + oo) * stride + base8);
            float4 A = g[0], B = g[1];
            float4* d = (float4*)&wl[(il * 64 + oo) * 8];
            d[0] = A; d[1] = B;
        }
        if (t < 256) {
            int bb = t >> 7, il = (t >> 4) & 7, kk = (t >> 1) & 7, ri = t & 1;
            xl[t] = Xs[((size_t)(((bb * 64 + i0 + il) * 23 + n) * 23 + m) * 8 + kk) * 2 + ri];
        }
        __syncthreads();
#pragma unroll
        for (int il = 0; il < 8; il++) {
            float wv = wl[(il * 64 + o) * 8 + tt];
            float xr0 = xl[(il * 8 + tt) * 2], xi0 = xl[(il * 8 + tt) * 2 + 1];
            float xr1 = xl[128 + (il * 8 + tt) * 2], xi1 = xl[128 + (il * 8 + tt) * 2 + 1];
            aR0 += wv * xr0; aI0 += wv * xi0;
            aR1 += wv * xr1; aI1 += wv * xi1;
        }
        __syncthreads();
    }
    size_t ob0 = ((size_t)((o * 23 + n) * 23 + m) * 8 + tt) * 2;
    size_t ob1 = ((size_t)(((64 + o) * 23 + n) * 23 + m) * 8 + tt) * 2;
    Md[ob0] = aR0; Md[ob0 + 1] = aI0;
    Md[ob1] = aR1; Md[ob1 + 1] = aI1;
}

// ---------------- inverse y (23 -> 64) ----------------
__global__ void k_inv_y(const float* __restrict__ Md, const float* __restrict__ txi,
                        float* __restrict__ T1) {
    int bid = blockIdx.x;
    int b = bid / 1472, rem = bid % 1472, o = rem / 23, m = rem % 23;
    int t = threadIdx.x;
    __shared__ float s[368];  // [n][k][2]
    if (t < 184) {
        int n = t >> 3, kk = t & 7;
        size_t g = ((size_t)(((b * 64 + o) * 23 + n) * 23 + m) * 8 + kk) * 2;
        s[t * 2] = Md[g]; s[t * 2 + 1] = Md[g + 1];
    }
    __syncthreads();
    int y = t >> 3, k = t & 7;
    float sr = 0.f, si = 0.f;
    for (int n = 0; n < 23; n++) {
        float ar = s[(n * 8 + k) * 2], ai = s[(n * 8 + k) * 2 + 1];
        float tr = txi[(y * 23 + n) * 2], ti = txi[(y * 23 + n) * 2 + 1];
        sr += ar * tr - ai * ti;
        si += ar * ti + ai * tr;
    }
    size_t g = ((size_t)(((b * 64 + o) * 64 + y) * 23 + m) * 8 + k) * 2;
    T1[g] = sr; T1[g + 1] = si;
}

// ---------------- inverse x (23 -> 64) ----------------
__global__ void k_inv_x(const float* __restrict__ T1, const float* __restrict__ txi,
                        float* __restrict__ T2) {
    int bid = blockIdx.x;
    int b = bid >> 12, o = (bid >> 6) & 63, y = bid & 63;
    int t = threadIdx.x;
    __shared__ float s[368];  // [m][k][2]
    if (t < 184) {
        size_t g = (size_t)(((b * 64 + o) * 64 + y)) * 368 + t * 2;
        s[t * 2] = T1[g]; s[t * 2 + 1] = T1[g + 1];
    }
    __syncthreads();
    int xx = t >> 3, k = t & 7;
    float sr = 0.f, si = 0.f;
    for (int m = 0; m < 23; m++) {
        float ar = s[(m * 8 + k) * 2], ai = s[(m * 8 + k) * 2 + 1];
        float tr = txi[(xx * 23 + m) * 2], ti = txi[(xx * 23 + m) * 2 + 1];
        sr += ar * tr - ai * ti;
        si += ar * ti + ai * tr;
    }
    size_t g = ((size_t)((b * 64 + o) * 4096 + y * 64 + xx) * 8 + k) * 2;
    T2[g] = sr; T2[g + 1] = si;
}

// ---------------- inline erf-based GELU (A&S 7.1.26, |err|<=1.5e-7) ----
__device__ __forceinline__ float gelu_fast(float x) {
    float u = x * 0.70710678118654752f;
    float a = fabsf(u);
    float t = 1.0f / (1.0f + 0.3275911f * a);
    float poly = t * (0.254829592f + t * (-0.284496736f + t * (1.421413741f +
                 t * (-1.453152027f + t * 1.061405429f))));
    float erfa = 1.0f - poly * __expf(-a * a);
    float er = copysignf(erfa, u);
    return 0.5f * x * (1.0f + er);
}

// ---------------- mlp1: c2r inverse-z + GEMM1 + gelu -> g[j][P] ----------------
// 64 NAMED accumulators (one per j); rolled i-loop streams T2 rows.
// No arrays, no LDS -> nothing to spill, no occupancy trap.
__global__ __launch_bounds__(256) void k_mlp1(
    const float* __restrict__ t2buf, const float* __restrict__ w1t,
    const float* __restrict__ b1, const float* __restrict__ tz2,
    float* __restrict__ g) {
    int gid = blockIdx.x * 256 + threadIdx.x;  // 327680
    int b = gid / 163840, p = gid % 163840;
    int y = p / 2560, xx = (p / 40) % 64, z = p % 40;
    const float4* tzp = (const float4*)(tz2 + z * 16);
    float4 Tz0 = tzp[0], Tz1 = tzp[1], Tz2 = tzp[2], Tz3 = tzp[3];
    float tc0 = Tz0.x;
    float tc1 = Tz0.z, ts1 = Tz0.w;
    float tc2 = Tz1.x, ts2 = Tz1.y, tc3 = Tz1.z, ts3 = Tz1.w;
    float tc4 = Tz2.x, ts4 = Tz2.y, tc5 = Tz2.z, ts5 = Tz2.w;
    float tc6 = Tz3.x, ts6 = Tz3.y, tc7 = Tz3.z, ts7 = Tz3.w;
    size_t rowbase = ((size_t)(b * 64) * 4096 + y * 64 + xx) * 16;
#define DECL(n) float h##n = b1[n];
    REP64(DECL)
#undef DECL
    for (int i = 0; i < 64; i++) {
        const float4* rp = (const float4*)(t2buf + rowbase + (size_t)i * 65536);
        float4 A = rp[0], B = rp[1], C = rp[2], D = rp[3];
        float xi = A.x * tc0;              // k=0: Im(DC) dropped (pocketfft c2r)
        xi = fmaf(A.z, tc1, xi); xi = fmaf(A.w, ts1, xi);
        xi = fmaf(B.x, tc2, xi); xi = fmaf(B.y, ts2, xi);
        xi = fmaf(B.z, tc3, xi); xi = fmaf(B.w, ts3, xi);
        xi = fmaf(C.x, tc4, xi); xi = fmaf(C.y, ts4, xi);
        xi = fmaf(C.z, tc5, xi); xi = fmaf(C.w, ts5, xi);
        xi = fmaf(D.x, tc6, xi); xi = fmaf(D.y, ts6, xi);
        xi = fmaf(D.z, tc7, xi); xi = fmaf(D.w, ts7, xi);
        const float* wr = w1t + i * 64;    // w1t[i][j] contiguous -> s_load runs
#define FMA(n) h##n = fmaf(wr[n], xi, h##n);
        REP64(FMA)
#undef FMA
    }
#define STO(n) g[(size_t)(n) * 327680 + gid] = gelu_fast(h##n);
    REP64(STO)
#undef STO
}

// ---------------- mlp2: GEMM2 + skip + relu, in-place on x ----------------
// 64 NAMED accumulators; skip-x and g streamed with rolled loops. ALL reads
// (x phase 1, g phase 2) complete before the first store -> in-place safe.
__global__ __launch_bounds__(256) void k_mlp2(
    const float* __restrict__ g, float* __restrict__ x,
    const float* __restrict__ w2t, const float* __restrict__ b2,
    const float* __restrict__ wwt, const float* __restrict__ wb, int dorelu) {
    int gid = blockIdx.x * 256 + threadIdx.x;  // 327680
    int b = gid / 163840, p = gid % 163840;
    size_t colbase = (size_t)b * 10485760 + p;
#define DECL(n) float h##n = b2[n] + wb[n];
    REP64(DECL)
#undef DECL
    for (int i = 0; i < 64; i++) {
        float xi = x[colbase + (size_t)i * 163840];
        const float* wr = wwt + i * 64;
#define FMA(n) h##n = fmaf(wr[n], xi, h##n);
        REP64(FMA)
#undef FMA
    }
    for (int j = 0; j < 64; j++) {
        float gj = g[(size_t)j * 327680 + gid];
        const float* wr = w2t + j * 64;
#define FMA(n) h##n = fmaf(wr[n], gj, h##n);
        REP64(FMA)
#undef FMA
    }
    if (dorelu) {
#define STO(n) x[colbase + (size_t)(n) * 163840] = fmaxf(h##n, 0.0f);
        REP64(STO)
#undef STO
    } else {
#define STO(n) x[colbase + (size_t)(n) * 163840] = h##n;
        REP64(STO)
#undef STO
    }
}

// ---------------- final head ----------------
// 64 NAMED x registers loaded once; j-loop rolled, 4 independent FMA chains.
__global__ __launch_bounds__(256) void k_head(
    const float* __restrict__ xcur,
    const float* __restrict__ qw1, const float* __restrict__ qb1,
    const float* __restrict__ qw2, const float* __restrict__ qb2,
    float* __restrict__ outp) {
    int gid = blockIdx.x * 256 + threadIdx.x;  // 327680
    int b = gid / 163840, p = gid % 163840;
    size_t base = (size_t)b * 10485760 + p;
#define LD(n) float x##n = xcur[base + (size_t)(n) * 163840];
    REP64(LD)
#undef LD
    float acc = qb2[0];
    for (int j = 0; j < 256; j += 4) {
        float h0 = qb1[j], h1 = qb1[j + 1], h2 = qb1[j + 2], h3 = qb1[j + 3];
        const float* w0 = qw1 + j * 64;
#define FMA(n) h0 = fmaf(w0[n], x##n, h0); \
               h1 = fmaf(w0[64 + n], x##n, h1); \
               h2 = fmaf(w0[128 + n], x##n, h2); \
               h3 = fmaf(w0[192 + n], x##n, h3);
        REP64(FMA)
#undef FMA
        acc += qw2[j] * gelu_fast(h0) + qw2[j + 1] * gelu_fast(h1) +
               qw2[j + 2] * gelu_fast(h2) + qw2[j + 3] * gelu_fast(h3);
    }
    outp[gid] = acc;
}

extern "C" void kernel_launch(void* const* d_in, const int* in_sizes, int n_in,
                              void* d_out, int out_size, void* d_ws, size_t ws_size,
                              hipStream_t stream) {
    const float* x_in = (const float*)d_in[0];
    const float* p_w  = (const float*)d_in[1];
    const float* p_b  = (const float*)d_in[2];
    const float* W_LC = (const float*)d_in[3];
    const float* W_LR = (const float*)d_in[4];
    const float* m_w1 = (const float*)d_in[5];
    const float* m_b1 = (const float*)d_in[6];
    const float* m_w2 = (const float*)d_in[7];
    const float* m_b2 = (const float*)d_in[8];
    const float* w_w  = (const float*)d_in[9];
    const float* w_b  = (const float*)d_in[10];
    const float* q_w1 = (const float*)d_in[11];
    const float* q_b1 = (const float*)d_in[12];
    const float* q_w2 = (const float*)d_in[13];
    const float* q_b2 = (const float*)d_in[14];

    char* ws = (char*)d_ws;
    // packed table region [0, 32768)
    float* tzf = (float*)(ws + 0);        // 2560 B
    float* tzi = (float*)(ws + 2560);     // 2560 B
    float* tz2 = (float*)(ws + 5120);     // 2560 B (16B-aligned)
    float* txf = (float*)(ws + 7680);     // 11776 B
    float* txi = (float*)(ws + 19456);    // 11776 B -> ends 31232
    float* w2t = (float*)(ws + 32768);
    float* wwt = (float*)(ws + 98304);
    float* w1t = (float*)(ws + 163840);
    size_t off = 229376;
    float* xA = (float*)(ws + off); off += 83886080ull;
    float* gbuf = (float*)(ws + off); off += 83886080ull;   // g[j][P]
    float* Fx = (float*)(ws + off); off += 12058624ull;
    float* Xs = (float*)(ws + off); off += 4333568ull;
    float* Md = (float*)(ws + off); off += 4333568ull;
    float* T1 = (float*)(ws + off); off += 12058624ull;
    float* T2 = (float*)(ws + off); off += 33554432ull;

    k_tables<<<6, 256, 0, stream>>>(tzf, tzi, tz2, txf, txi);
    k_wtrans<<<64, 256, 0, stream>>>(m_w2, w_w, m_w1, w2t, wwt, w1t);
    k_lift<<<1280, 256, 0, stream>>>(x_in, p_w, p_b, xA);

    for (int l = 0; l < 4; l++) {
        k_fwd_zx<<<8192, 256, 0, stream>>>(xA, tzf, txf, Fx);
        k_fwd_y<<<2944, 192, 0, stream>>>(Fx, txf, Xs);
        k_mix<<<529, 512, 0, stream>>>(Xs, W_LC + (size_t)l * 393216,
                                       W_LR + (size_t)l * 3964928, Md);
        k_inv_y<<<2944, 512, 0, stream>>>(Md, txi, T1);
        k_inv_x<<<8192, 512, 0, stream>>>(T1, txi, T2);
        k_mlp1<<<1280, 256, 0, stream>>>(T2, w1t + (size_t)l * 4096, m_b1 + l * 64,
                                         tz2, gbuf);
        k_mlp2<<<1280, 256, 0, stream>>>(gbuf, xA, w2t + (size_t)l * 4096, m_b2 + l * 64,
                                         wwt + (size_t)l * 4096, w_b + l * 64,
                                         (l < 3) ? 1 : 0);
    }
    k_head<<<1280, 256, 0, stream>>>(xA, q_w1, q_b1, q_w2, q_b2, (float*)d_out);
}